// Round 10
// baseline (33.744 us; speedup 1.0000x reference)
//
#include <hip/hip_runtime.h>
#include <math.h>

// Problem constants (match reference)
#define Bb   16
#define Cc   3
#define Hh   64
#define Ww   64
#define Kk   32
#define Ss   32
#define OHh  60
#define OWw  60
#define Pp   3600
#define OHSUB 15           // output rows per block (4 strips)
#define ROWS 19            // staged rows per block: 15 + R-1
#define NGRP 225           // 15 rows * 15 groups of 4 columns
#define TPB  256

// f32 LDS layout: row = 66 floats (64 data + 2 pad; EVEN stride -> every
// even-column gather is 8B-aligned). Two copies: copy0[p] = x[p],
// copy1[p] = x[p+1]. A leaf at col w reads copy (w&1) at col (w - (w&1)):
// 4 consecutive px = floats [d..d+3], d even -> two float2 loads that the
// DS-combiner merges into one ds_read2_b64. NO fp16 converts anywhere.
#define FROW  66
#define FCH   (ROWS * FROW)   // 1254 floats per channel
#define FCOPY (Cc * FCH)      // 3762 floats per copy

typedef float vf4 __attribute__((ext_vector_type(4)));
typedef float vf4u __attribute__((ext_vector_type(4), aligned(4)));

#define SB __builtin_amdgcn_sched_barrier(0)

static __device__ __forceinline__ vf4 vsplat(float s) { return (vf4){s, s, s, s}; }

// combine: y = c0 + a*dA + b*dB + a*b*dAB  (c = {c0, dA, dB, dAB})
static __device__ __forceinline__ vf4 comb(vf4 a, vf4 b, vf4 c) {
    const vf4 t = __builtin_elementwise_fma(b, vsplat(c.w), vsplat(c.y));
    const vf4 u = __builtin_elementwise_fma(b, vsplat(c.z), vsplat(c.x));
    return __builtin_elementwise_fma(a, t, u);
}

// gather 4 consecutive px of one leaf-input: two adjacent float2 LDS reads
// (8B-aligned; merged to ds_read2_b64), f32 -> zero converts
#define GATH(fbase, dst)                                                     \
    {                                                                        \
        const float2 lo = *reinterpret_cast<const float2*>(&xsh[(fbase) + loff]);     \
        const float2 hi = *reinterpret_cast<const float2*>(&xsh[(fbase) + loff + 2]); \
        dst = (vf4){lo.x, lo.y, hi.x, hi.y};                                 \
    }

// One SUB4 stage: 8 LDS gathers then FMA cluster, SB-pinned boundary
// (bounds scheduler live-ranges: no scratch spills).
#define STAGE(S, LASTQ, FOLD)                                                 \
    vf4 t4_##S;                                                               \
    {                                                                         \
        vf4 A0, B0, A1, B1, A2, B2, A3, B3;                                   \
        GATH(cb0.x, A0); GATH(cb0.y, B0);                                     \
        GATH(cb1.x, A1); GATH(cb1.y, B1);                                     \
        GATH(cb2.x, A2); GATH(cb2.y, B2);                                     \
        GATH(cb3.x, A3); GATH(cb3.y, B3);                                     \
        const vf4 c0 = coefs[4*S], c1 = coefs[4*S+1];                         \
        const vf4 c2 = coefs[4*S+2], c3 = coefs[4*S+3];                       \
        const vf4 d0 = coefs[32+2*S], d1 = coefs[33+2*S], e0 = coefs[48+S];   \
        if constexpr (!(LASTQ)) {                                             \
            cb0 = bases[(4*S+4) & 31]; cb1 = bases[(4*S+5) & 31];             \
            cb2 = bases[(4*S+6) & 31]; cb3 = bases[(4*S+7) & 31];             \
        }                                                                     \
        const vf4 u0 = comb(A0, B0, c0), u1 = comb(A1, B1, c1);               \
        const vf4 u2 = comb(A2, B2, c2), u3 = comb(A3, B3, c3);               \
        t4_##S = comb(comb(u0, u1, d0), comb(u2, u3, d1), e0);                \
        FOLD                                                                  \
        SB;                                                                   \
    }

__global__ __launch_bounds__(TPB) void logic_conv_kernel(
    const float* __restrict__ x,
    const int*   __restrict__ h_idx,
    const int*   __restrict__ w_idx,
    const int*   __restrict__ c_idx,
    const float* __restrict__ w0, const float* __restrict__ w1,
    const float* __restrict__ w2, const float* __restrict__ w3,
    const float* __restrict__ w4, const float* __restrict__ w5,
    float* __restrict__ out)
{
    __shared__ float xsh[2 * FCOPY];   // 30,096 B
    __shared__ vf4   coefs[63];
    __shared__ int2  bases[32];

    const int tid   = threadIdx.x;
    const int blk   = blockIdx.x;
    const int k     = blk & 31;          // fastest: 32 consecutive blocks share x rows (L2)
    const int strip = (blk >> 5) & 3;
    const int b     = blk >> 7;
    const int oh0   = strip * OHSUB;

    // ---- stage rows [oh0, oh0+19) of x[b] as f32, two shifted copies ----
    const float* xb = x + b * (Cc * Hh * Ww);
    #pragma unroll
    for (int it = 0; it < 4; ++it) {
        const int flat = it * TPB + tid;           // chunk of 4 floats, 0..911
        if (flat < Cc * ROWS * 16) {
            const int c   = flat / (ROWS * 16);    // /304
            const int rem = flat - c * (ROWS * 16);
            const int r   = rem >> 4;
            const int j   = rem & 15;
            const float* src = xb + c * (Hh * Ww) + (oh0 + r) * Ww + (j << 2);
            const vf4u A = *reinterpret_cast<const vf4u*>(src);
            vf4u Bv;
            if (j < 15) Bv = *reinterpret_cast<const vf4u*>(src + 1);
            else        Bv = (vf4u){A.y, A.z, A.w, A.w};   // tail pad, never read
            const int di = c * FCH + r * FROW + (j << 2);  // even -> 8B-aligned
            *reinterpret_cast<float2*>(&xsh[di])              = make_float2(A.x, A.y);
            *reinterpret_cast<float2*>(&xsh[di + 2])          = make_float2(A.z, A.w);
            *reinterpret_cast<float2*>(&xsh[FCOPY + di])      = make_float2(Bv.x, Bv.y);
            *reinterpret_cast<float2*>(&xsh[FCOPY + di + 2])  = make_float2(Bv.z, Bv.w);
        }
    }

    // ---- gather bases: float index of each leaf-input (copy by col parity) ----
    if (tid < 32) {
        const int i0 = (0 * Kk + k) * Ss + tid;
        const int i1 = (1 * Kk + k) * Ss + tid;
        const int wA = w_idx[i0], sA = wA & 1;
        const int wB = w_idx[i1], sB = wB & 1;
        bases[tid] = make_int2(
            sA * FCOPY + c_idx[i0] * FCH + h_idx[i0] * FROW + (wA - sA),
            sB * FCOPY + c_idx[i1] * FCH + h_idx[i1] * FROW + (wB - sB));
    }

    // ---- per-node coefficients: softmax(w)/LUT folded to 4 floats ----
    if (tid >= 64 && tid < 127) {
        const int t = tid - 64;
        const float* wp; int n;
        if      (t < 32) { wp = w0; n = t;      }
        else if (t < 48) { wp = w1; n = t - 32; }
        else if (t < 56) { wp = w2; n = t - 48; }
        else if (t < 60) { wp = w3; n = t - 56; }
        else if (t < 62) { wp = w4; n = t - 60; }
        else             { wp = w5; n = 0;      }
        const float* lg = wp + (n * Kk + k) * 16;
        float l[16];
        float m = lg[0];
        #pragma unroll
        for (int q = 0; q < 16; ++q) { l[q] = lg[q]; m = fmaxf(m, l[q]); }
        float e[16], s = 0.f;
        #pragma unroll
        for (int q = 0; q < 16; ++q) { e[q] = __expf(l[q] - m); s += e[q]; }
        const float inv = 1.f / s;
        float c0 = 0.f, c1 = 0.f, c2 = 0.f, c3 = 0.f;
        #pragma unroll
        for (int op = 0; op < 16; ++op) {
            if (op & 1) c0 += e[op];
            if (op & 2) c1 += e[op];
            if (op & 4) c2 += e[op];
            if (op & 8) c3 += e[op];
        }
        c0 *= inv; c1 *= inv; c2 *= inv; c3 *= inv;
        coefs[t] = (vf4){c0, c2 - c0, c1 - c0, c0 - c1 - c2 + c3};
    }

    __syncthreads();

    // ---- main: one 4-px group per thread, oh-major ----
    if (tid < NGRP) {
        const int oh   = tid % OHSUB;              // consecutive lanes -> rows
        const int owg  = tid / OHSUB;              // 0..14
        const int loff = oh * FROW + (owg << 2);   // even -> 8B-aligned

        int2 cb0 = bases[0], cb1 = bases[1], cb2 = bases[2], cb3 = bases[3];
        vf4 t8a, t8b, t16a, t16b, y;

        STAGE(0, 0, )
        STAGE(1, 0, t8a = comb(t4_0, t4_1, coefs[56]);)
        STAGE(2, 0, )
        STAGE(3, 0, t8b = comb(t4_2, t4_3, coefs[57]);
                    t16a = comb(t8a, t8b, coefs[60]);)
        STAGE(4, 0, )
        STAGE(5, 0, t8a = comb(t4_4, t4_5, coefs[58]);)
        STAGE(6, 0, )
        STAGE(7, 1, t8b = comb(t4_6, t4_7, coefs[59]);
                    t16b = comb(t8a, t8b, coefs[61]);
                    y = comb(t16a, t16b, coefs[62]);)

        float* outp = out + (b * Kk + k) * Pp + (oh0 + oh) * OWw + (owg << 2);
        *reinterpret_cast<vf4*>(outp) = y;
    }
}

extern "C" void kernel_launch(void* const* d_in, const int* in_sizes, int n_in,
                              void* d_out, int out_size, void* d_ws, size_t ws_size,
                              hipStream_t stream) {
    const float* x     = (const float*)d_in[0];
    const int*   h_idx = (const int*)d_in[1];
    const int*   w_idx = (const int*)d_in[2];
    const int*   c_idx = (const int*)d_in[3];
    const float* w0    = (const float*)d_in[4];
    const float* w1    = (const float*)d_in[5];
    const float* w2    = (const float*)d_in[6];
    const float* w3    = (const float*)d_in[7];
    const float* w4    = (const float*)d_in[8];
    const float* w5    = (const float*)d_in[9];
    float* out = (float*)d_out;

    dim3 grid(Bb * Kk * 4);   // 2048 blocks: (b, strip, k) with k fastest
    dim3 block(TPB);
    hipLaunchKernelGGL(logic_conv_kernel, grid, block, 0, stream,
                       x, h_idx, w_idx, c_idx, w0, w1, w2, w3, w4, w5, out);
}

// Round 11
// 23.178 us; speedup vs baseline: 1.4559x; 1.4559x over previous
//
#include <hip/hip_runtime.h>
#include <hip/hip_fp16.h>
#include <math.h>

// Problem constants (match reference)
#define Bb   16
#define Cc   3
#define Hh   64
#define Ww   64
#define Kk   32
#define Ss   32
#define OHh  60
#define OWw  60
#define Pp   3600
#define ROWS 34            // staged rows per block: 30 output rows + R-1
#define OHSUB 30
#define TPB  256

// fp16 LDS layout (dword units): row = 33 dwords (66 halfs: 64 data + pad).
// Bank stride per row = 33 mod 32 = 1 -> oh-major lanes are conflict-free.
// Two copies: S0[p] = x[p], S1[p] = x[p+1]; a leaf at col w reads copy (w&1)
// at half (w - (w&1)) -> every 4-px gather is one dword pair (ds_read2_b32).
#define DWROW  33
#define DWC    (ROWS * DWROW)   // 1122 dwords per channel
#define DWCOPY (Cc * DWC)       // 3366 dwords per copy

typedef float vf4 __attribute__((ext_vector_type(4)));
typedef float vf4u __attribute__((ext_vector_type(4), aligned(4)));

#define SB __builtin_amdgcn_sched_barrier(0)

static __device__ __forceinline__ vf4 vsplat(float s) { return (vf4){s, s, s, s}; }

// combine: y = c0 + a*dA + b*dB + a*b*dAB  (c = {c0, dA, dB, dAB})
static __device__ __forceinline__ vf4 comb(vf4 a, vf4 b, vf4 c) {
    const vf4 t = __builtin_elementwise_fma(b, vsplat(c.w), vsplat(c.y));
    const vf4 u = __builtin_elementwise_fma(b, vsplat(c.z), vsplat(c.x));
    return __builtin_elementwise_fma(a, t, u);
}

// pack two f32 -> one dword of two f16 (RTE)
static __device__ __forceinline__ unsigned int pkh(float lo, float hi) {
    __half2 h = __floats2half2_rn(lo, hi);
    return *reinterpret_cast<unsigned int*>(&h);
}

// gather 4 consecutive px of one leaf-input at row-offset lofs
#define GATH(dbase, lofs, dst)                                               \
    {                                                                        \
        const unsigned int lo = xsh[(dbase) + (lofs)];                       \
        const unsigned int hi = xsh[(dbase) + (lofs) + 1];                   \
        const __half2 hl = *reinterpret_cast<const __half2*>(&lo);           \
        const __half2 hh = *reinterpret_cast<const __half2*>(&hi);           \
        const float2 fl = __half22float2(hl);                                \
        const float2 fh = __half22float2(hh);                                \
        dst = (vf4){fl.x, fl.y, fh.x, fh.y};                                 \
    }

// One SUB4 stage, TWO pixel-groups (rows oh and oh+15) sharing the stage's
// 7 coef b128 + 4 base b64 LDS reads. SB bounds live ranges (no spill).
#define STAGE(S, LASTQ, FOLD)                                                 \
    vf4 t4a_##S, t4b_##S;                                                     \
    {                                                                         \
        vf4 Aa0,Ba0,Aa1,Ba1,Aa2,Ba2,Aa3,Ba3;                                  \
        vf4 Ab0,Bb0,Ab1,Bb1,Ab2,Bb2,Ab3,Bb3;                                  \
        GATH(cb0.x, loffA, Aa0); GATH(cb0.y, loffA, Ba0);                     \
        GATH(cb1.x, loffA, Aa1); GATH(cb1.y, loffA, Ba1);                     \
        GATH(cb2.x, loffA, Aa2); GATH(cb2.y, loffA, Ba2);                     \
        GATH(cb3.x, loffA, Aa3); GATH(cb3.y, loffA, Ba3);                     \
        GATH(cb0.x, loffB, Ab0); GATH(cb0.y, loffB, Bb0);                     \
        GATH(cb1.x, loffB, Ab1); GATH(cb1.y, loffB, Bb1);                     \
        GATH(cb2.x, loffB, Ab2); GATH(cb2.y, loffB, Bb2);                     \
        GATH(cb3.x, loffB, Ab3); GATH(cb3.y, loffB, Bb3);                     \
        const vf4 c0 = coefs[4*S], c1 = coefs[4*S+1];                         \
        const vf4 c2 = coefs[4*S+2], c3 = coefs[4*S+3];                       \
        const vf4 d0 = coefs[32+2*S], d1 = coefs[33+2*S], e0 = coefs[48+S];   \
        if constexpr (!(LASTQ)) {                                             \
            cb0 = bases[(4*S+4) & 31]; cb1 = bases[(4*S+5) & 31];             \
            cb2 = bases[(4*S+6) & 31]; cb3 = bases[(4*S+7) & 31];             \
        }                                                                     \
        vf4 u0 = comb(Aa0, Ba0, c0), u1 = comb(Aa1, Ba1, c1);                 \
        vf4 u2 = comb(Aa2, Ba2, c2), u3 = comb(Aa3, Ba3, c3);                 \
        t4a_##S = comb(comb(u0, u1, d0), comb(u2, u3, d1), e0);               \
        u0 = comb(Ab0, Bb0, c0); u1 = comb(Ab1, Bb1, c1);                     \
        u2 = comb(Ab2, Bb2, c2); u3 = comb(Ab3, Bb3, c3);                     \
        t4b_##S = comb(comb(u0, u1, d0), comb(u2, u3, d1), e0);               \
        FOLD                                                                  \
        SB;                                                                   \
    }

__global__ __launch_bounds__(TPB) void logic_conv_kernel(
    const float* __restrict__ x,
    const int*   __restrict__ h_idx,
    const int*   __restrict__ w_idx,
    const int*   __restrict__ c_idx,
    const float* __restrict__ w0, const float* __restrict__ w1,
    const float* __restrict__ w2, const float* __restrict__ w3,
    const float* __restrict__ w4, const float* __restrict__ w5,
    float* __restrict__ out)
{
    __shared__ unsigned int xsh[2 * DWCOPY];   // 26,928 B
    __shared__ vf4  coefs[63];
    __shared__ int2 bases[32];

    const int tid  = threadIdx.x;
    const int blk  = blockIdx.x;
    const int b    = blk >> 6;          // 16 images
    const int k    = (blk >> 1) & 31;   // 32 filters
    const int half = blk & 1;           // row-half of the output
    const int oh0  = half * OHSUB;

    // ---- stage rows [oh0, oh0+34) of x[b] as fp16, two shifted copies ----
    const float* xb = x + b * (Cc * Hh * Ww);
    #pragma unroll
    for (int it = 0; it < 7; ++it) {
        const int flat = it * TPB + tid;           // chunk of 4 floats, 0..1631
        if (flat < Cc * ROWS * 16) {
            const int c   = flat / (ROWS * 16);    // /544
            const int rem = flat - c * (ROWS * 16);
            const int r   = rem >> 4;
            const int w4i = rem & 15;
            const int w0c = w4i << 2;
            const float* src = xb + c * (Hh * Ww) + (oh0 + r) * Ww + w0c;
            const vf4u A = *reinterpret_cast<const vf4u*>(src);
            vf4u Bv;
            if (w4i < 15) Bv = *reinterpret_cast<const vf4u*>(src + 1);
            else          Bv = (vf4u){A.y, A.z, A.w, A.w};   // tail pad, never read
            const int di = c * DWC + r * DWROW + (w0c >> 1);
            xsh[di]              = pkh(A.x, A.y);
            xsh[di + 1]          = pkh(A.z, A.w);
            xsh[DWCOPY + di]     = pkh(Bv.x, Bv.y);
            xsh[DWCOPY + di + 1] = pkh(Bv.z, Bv.w);
        }
    }

    // ---- gather bases: dword index of each leaf-input (copy by col parity) ----
    if (tid < 32) {
        const int i0 = (0 * Kk + k) * Ss + tid;
        const int i1 = (1 * Kk + k) * Ss + tid;
        const int wA = w_idx[i0], sA = wA & 1;
        const int wB = w_idx[i1], sB = wB & 1;
        bases[tid] = make_int2(
            sA * DWCOPY + c_idx[i0] * DWC + h_idx[i0] * DWROW + ((wA - sA) >> 1),
            sB * DWCOPY + c_idx[i1] * DWC + h_idx[i1] * DWROW + ((wB - sB) >> 1));
    }

    // ---- per-node coefficients: softmax(w)/LUT folded to 4 floats ----
    if (tid >= 64 && tid < 127) {
        const int t = tid - 64;
        const float* wp; int n;
        if      (t < 32) { wp = w0; n = t;      }
        else if (t < 48) { wp = w1; n = t - 32; }
        else if (t < 56) { wp = w2; n = t - 48; }
        else if (t < 60) { wp = w3; n = t - 56; }
        else if (t < 62) { wp = w4; n = t - 60; }
        else             { wp = w5; n = 0;      }
        const float* lg = wp + (n * Kk + k) * 16;
        float l[16];
        float m = lg[0];
        #pragma unroll
        for (int q = 0; q < 16; ++q) { l[q] = lg[q]; m = fmaxf(m, l[q]); }
        float e[16], s = 0.f;
        #pragma unroll
        for (int q = 0; q < 16; ++q) { e[q] = __expf(l[q] - m); s += e[q]; }
        const float inv = 1.f / s;
        float c0 = 0.f, c1 = 0.f, c2 = 0.f, c3 = 0.f;
        #pragma unroll
        for (int op = 0; op < 16; ++op) {
            if (op & 1) c0 += e[op];
            if (op & 2) c1 += e[op];
            if (op & 4) c2 += e[op];
            if (op & 8) c3 += e[op];
        }
        c0 *= inv; c1 *= inv; c2 *= inv; c3 *= inv;
        coefs[t] = (vf4){c0, c2 - c0, c1 - c0, c0 - c1 - c2 + c3};
    }

    __syncthreads();

    // ---- main: two 4-px groups per thread (rows oh and oh+15, same owg),
    //      sharing coef/base LDS reads; oh-major lanes -> conflict-free ----
    if (tid < 225) {
        const int oh    = tid % 15;                 // consecutive lanes -> rows
        const int owg   = tid / 15;                 // 0..14
        const int loffA = oh * DWROW + (owg << 1);  // group A: row oh
        const int loffB = loffA + 15 * DWROW;       // group B: row oh+15

        int2 cb0 = bases[0], cb1 = bases[1], cb2 = bases[2], cb3 = bases[3];
        vf4 p8aA, p8aB, p8bA, p8bB, t16aA, t16aB, t16bA, t16bB, yA, yB;

        STAGE(0, 0, )
        STAGE(1, 0, p8aA = comb(t4a_0, t4a_1, coefs[56]);
                    p8aB = comb(t4b_0, t4b_1, coefs[56]);)
        STAGE(2, 0, )
        STAGE(3, 0, p8bA = comb(t4a_2, t4a_3, coefs[57]);
                    p8bB = comb(t4b_2, t4b_3, coefs[57]);
                    t16aA = comb(p8aA, p8bA, coefs[60]);
                    t16aB = comb(p8aB, p8bB, coefs[60]);)
        STAGE(4, 0, )
        STAGE(5, 0, p8aA = comb(t4a_4, t4a_5, coefs[58]);
                    p8aB = comb(t4b_4, t4b_5, coefs[58]);)
        STAGE(6, 0, )
        STAGE(7, 1, p8bA = comb(t4a_6, t4a_7, coefs[59]);
                    p8bB = comb(t4b_6, t4b_7, coefs[59]);
                    t16bA = comb(p8aA, p8bA, coefs[61]);
                    t16bB = comb(p8aB, p8bB, coefs[61]);
                    yA = comb(t16aA, t16bA, coefs[62]);
                    yB = comb(t16aB, t16bB, coefs[62]);)

        float* outp = out + (b * Kk + k) * Pp + (oh0 + oh) * OWw + (owg << 2);
        *reinterpret_cast<vf4*>(outp)                = yA;
        *reinterpret_cast<vf4*>(outp + 15 * OWw)     = yB;
    }
}

extern "C" void kernel_launch(void* const* d_in, const int* in_sizes, int n_in,
                              void* d_out, int out_size, void* d_ws, size_t ws_size,
                              hipStream_t stream) {
    const float* x     = (const float*)d_in[0];
    const int*   h_idx = (const int*)d_in[1];
    const int*   w_idx = (const int*)d_in[2];
    const int*   c_idx = (const int*)d_in[3];
    const float* w0    = (const float*)d_in[4];
    const float* w1    = (const float*)d_in[5];
    const float* w2    = (const float*)d_in[6];
    const float* w3    = (const float*)d_in[7];
    const float* w4    = (const float*)d_in[8];
    const float* w5    = (const float*)d_in[9];
    float* out = (float*)d_out;

    dim3 grid(Bb * Kk * 2);   // 1024 blocks: (b, k, row-half)
    dim3 block(TPB);
    hipLaunchKernelGGL(logic_conv_kernel, grid, block, 0, stream,
                       x, h_idx, w_idx, c_idx, w0, w1, w2, w3, w4, w5, out);
}